// Round 16
// baseline (1446.380 us; speedup 1.0000x reference)
//
#include <hip/hip_runtime.h>
#include <hip/hip_bf16.h>
#include <math.h>

// Problem constants
#define SEQ   2048
#define NROW  4096            // B*SEQ
#define DM    1024
#define LDQ   1024            // Q/K row stride (4 heads * 256)
#define LDV   2048            // V/O row stride (4 heads * 512)
#define NBLK  16              // 2048 / 128 row blocks per (b,h)

typedef float  f32x4  __attribute__((ext_vector_type(4)));
typedef int    i32x4  __attribute__((ext_vector_type(4)));
typedef __bf16 bf16x8 __attribute__((ext_vector_type(8)));

// Compiler-managed MFMA: hazards/NOPs/spills handled by the backend.
#define MFMA(d, a, b) (d) = __builtin_amdgcn_mfma_f32_16x16x32_bf16((a), (b), (d), 0, 0, 0)

__device__ inline ushort f2bf(float f) {
  __hip_bfloat16 h = __float2bfloat16(f);
  return *(ushort*)&h;
}
__device__ inline float bf2f(ushort u) {
  return __uint_as_float((unsigned)u << 16);
}
// v ~= bf2f(hi) + bf2f(lo), residual ~ 2^-18 * |v|
__device__ inline void split2(float v, ushort& hi, ushort& lo) {
  hi = f2bf(v);
  lo = f2bf(v - bf2f(hi));
}
__device__ inline bf16x8 ldfrag(const ushort* p) { return *(const bf16x8*)p; }

// Async global->LDS, 16B per lane. Both sides are linear in lane order here
// (dest byte offset = wave_base + lane*16), matching the HW's linear write.
__device__ inline void gload_lds16(const ushort* g, ushort* l) {
  __builtin_amdgcn_global_load_lds(
      (const __attribute__((address_space(1))) void*)g,
      (__attribute__((address_space(3))) void*)l, 16, 0, 0);
}

// ---------------------------------------------------------------------------
// Packing kernels (bf16 "k-chunk-major" MFMA operand layout):
// pack[blk][kc][r][8] holds element with k = kc*8+j  (16B-contiguous rows).
// ---------------------------------------------------------------------------
__global__ void pack_x_kernel(const float* __restrict__ X, ushort* __restrict__ P)
{
  const int t = blockIdx.x * 256 + threadIdx.x;   // < 4096*128
  const int kc = t & 127;
  const int m  = t >> 7;
  const float* src = X + (size_t)m * DM + kc * 8;
  f32x4 v0 = *(const f32x4*)src;
  f32x4 v1 = *(const f32x4*)(src + 4);
  ushort o[8];
  #pragma unroll
  for (int j = 0; j < 4; ++j) { o[j] = f2bf(v0[j]); o[4 + j] = f2bf(v1[j]); }
  ushort* dst = P + ((size_t)((m >> 7) * 128 + kc) * 128 + (m & 127)) * 8;
  *(i32x4*)dst = *(i32x4*)o;
}

__global__ void pack_w_kernel(const float* __restrict__ W, ushort* __restrict__ P,
                              int K, int N)
{
  const int K8 = K >> 3;
  const int t = blockIdx.x * 256 + threadIdx.x;   // < N*K/8
  const int c  = t & 127;
  const int kc = (t >> 7) % K8;
  const int nb = t / (128 * K8);
  ushort o[8];
  #pragma unroll
  for (int j = 0; j < 8; ++j)
    o[j] = f2bf(W[(size_t)(kc * 8 + j) * N + nb * 128 + c]);
  ushort* dst = P + ((size_t)(nb * K8 + kc) * 128 + c) * 8;
  *(i32x4*)dst = *(i32x4*)o;
}

// ---------------------------------------------------------------------------
// Fused RoPE + split-pack for ONE matrix (launched once for Q, once for K,
// in that order -- the K launch's destination aliases the dead Q fp32 buffer,
// which is only safe because the Q launch completed first).
// ---------------------------------------------------------------------------
__global__ void rope_pack1_kernel(const float* __restrict__ M,
                                  ushort* __restrict__ Phi, ushort* __restrict__ Plo)
{
  const int idx = blockIdx.x * 256 + threadIdx.x;  // < 4096*4*32
  const int g   = idx & 31;           // d-group (8 elements)
  const int h   = (idx >> 5) & 3;
  const int row = idx >> 7;           // 0..4095
  const int pos = row & (SEQ - 1);
  const int d0  = g * 8;
  const bool hihalf = d0 >= 128;
  const int f0 = d0 & 127;
  const float* mp = M + (size_t)row * LDQ + h * 256;
  ushort oh[8], ol[8];
  #pragma unroll
  for (int j = 0; j < 8; ++j) {
    const int f = f0 + j;
    const float inv = expf(-(float)f * (9.210340371976184f / 128.f));
    float s, c;
    sincosf((float)pos * inv, &s, &c);
    const float m1 = mp[f], m2 = mp[f + 128];
    const float mv = hihalf ? (m2 * c + m1 * s) : (m1 * c - m2 * s);
    split2(mv, oh[j], ol[j]);
  }
  const int b = row >> 11, r = row & 127, tb = (row & 2047) >> 7;
  const int bh = b * 4 + h;
  const size_t doff = (((size_t)(bh * 16 + tb) * 32 + g) * 128 + r) * 8;
  *(i32x4*)(Phi + doff) = *(i32x4*)oh;
  *(i32x4*)(Plo + doff) = *(i32x4*)ol;
}

// sol (fp32, one batch's 2048 rows of V) -> split B-pack, COALESCED layout:
// Sp[(h*16+jb)*2 + hl][kc 0..15][c 0..511][8]
__global__ void pack_sol_kernel(const float* __restrict__ Vb, ushort* __restrict__ Sp)
{
  const int hj = blockIdx.x;                         // h*16 + jb
  const int h  = hj >> 4, jb = hj & 15;
  const int c  = blockIdx.y * 256 + threadIdx.x;     // 0..511
  const float* src = Vb + (size_t)(jb * 128) * LDV + h * 512 + c;
  ushort* dhi = Sp + ((size_t)hj * 2    ) * 65536;
  ushort* dlo = Sp + ((size_t)hj * 2 + 1) * 65536;
  for (int kc = 0; kc < 16; ++kc) {
    ushort oh[8], ol[8];
    #pragma unroll
    for (int j = 0; j < 8; ++j)
      split2(src[(size_t)(kc * 8 + j) * LDV], oh[j], ol[j]);
    *(i32x4*)(dhi + ((size_t)kc * 512 + c) * 8) = *(i32x4*)oh;
    *(i32x4*)(dlo + ((size_t)kc * 512 + c) * 8) = *(i32x4*)ol;
  }
}

// ---------------------------------------------------------------------------
// bf16 MFMA GEMM: C[M,N] fp32 = Apack * Bpack. 128x128 tile, 4 waves 2x2.
// Staging via async global_load_lds (16B/lane, linear both sides).
// ---------------------------------------------------------------------------
__global__ __launch_bounds__(256) void gemm_bf16(
    const ushort* __restrict__ Ap, const ushort* __restrict__ Bp,
    float* __restrict__ C, int M, int N, int K)
{
  __shared__ __align__(16) ushort a_lds[8][128][8];
  __shared__ __align__(16) ushort b_lds[8][128][8];
  const int tid  = threadIdx.x;
  const int lane = tid & 63;
  const int w    = tid >> 6;
  const int wr   = w >> 1, wc = w & 1;
  const int mb = blockIdx.y, nb = blockIdx.x;
  const int K8 = K >> 3;
  const ushort* aT = Ap + (size_t)mb * K8 * 1024;
  const ushort* bT = Bp + (size_t)nb * K8 * 1024;
  const int lr = lane & 15;
  const int lk = lane >> 4;

  f32x4 acc[4][4];
  #pragma unroll
  for (int i = 0; i < 4; ++i)
    #pragma unroll
    for (int j = 0; j < 4; ++j) acc[i][j] = (f32x4)(0.f);

  for (int kc0 = 0; kc0 < K8; kc0 += 8) {
    const ushort* asrc = aT + (size_t)kc0 * 1024;
    const ushort* bsrc = bT + (size_t)kc0 * 1024;
    __syncthreads();   // previous iteration's LDS reads complete
    #pragma unroll
    for (int it = 0; it < 4; ++it) {
      gload_lds16(asrc + it * 2048 + tid * 8, ((ushort*)a_lds) + it * 2048 + tid * 8);
      gload_lds16(bsrc + it * 2048 + tid * 8, ((ushort*)b_lds) + it * 2048 + tid * 8);
    }
    __syncthreads();   // vmcnt drained by compiler before barrier
    #pragma unroll
    for (int kk = 0; kk < 2; ++kk) {
      bf16x8 af[4], bf[4];
      #pragma unroll
      for (int m = 0; m < 4; ++m)
        af[m] = ldfrag(&a_lds[kk * 4 + lk][wr * 64 + m * 16 + lr][0]);
      #pragma unroll
      for (int n = 0; n < 4; ++n)
        bf[n] = ldfrag(&b_lds[kk * 4 + lk][wc * 64 + n * 16 + lr][0]);
      #pragma unroll
      for (int m = 0; m < 4; ++m)
        #pragma unroll
        for (int n = 0; n < 4; ++n)
          MFMA(acc[m][n], af[m], bf[n]);
    }
  }
  const int r0 = (lane >> 4) * 4;
  #pragma unroll
  for (int m = 0; m < 4; ++m)
    #pragma unroll
    for (int n = 0; n < 4; ++n) {
      const int row = mb * 128 + wr * 64 + m * 16 + r0;
      const int col = nb * 128 + wc * 64 + n * 16 + lr;
      float* cp = C + (size_t)row * N + col;
      #pragma unroll
      for (int q = 0; q < 4; ++q) cp[(size_t)q * N] = acc[m][n][q];
    }
}

// ---------------------------------------------------------------------------
// winv: L = tril(exp(K_t K_t^T/16)) + eps*I via split-MFMA Gram, fp32 invert,
// store W = L^-1 as SPLIT bf16 A-packs (Whi + Wlo). (256 thr, 2x2 waves)
// ---------------------------------------------------------------------------
__global__ __launch_bounds__(256) void winv_kernel(
    const ushort* __restrict__ Khi, const ushort* __restrict__ Klo,
    ushort* __restrict__ Whi, ushort* __restrict__ Wlo)
{
  __shared__ float L[128][129];
  __shared__ float W[128][129];
  const int t = blockIdx.x, bh = blockIdx.y;
  const int tid = threadIdx.x;
  const int lane = tid & 63, w = tid >> 6;
  const int wr = w >> 1, wc = w & 1;
  const int lr = lane & 15, lk = lane >> 4;
  const size_t kb = (size_t)(bh * 16 + t) * 32768;

  f32x4 acc[4][4];
  #pragma unroll
  for (int i = 0; i < 4; ++i)
    #pragma unroll
    for (int j = 0; j < 4; ++j) acc[i][j] = (f32x4)(0.f);
  #pragma unroll
  for (int ks = 0; ks < 8; ++ks) {
    bf16x8 ah[4], al[4];
    #pragma unroll
    for (int m = 0; m < 4; ++m) {
      const size_t off = kb + ((size_t)(ks * 4 + lk) * 128 + wr * 64 + m * 16 + lr) * 8;
      ah[m] = ldfrag(Khi + off);
      al[m] = ldfrag(Klo + off);
    }
    #pragma unroll
    for (int n = 0; n < 4; ++n) {
      const size_t off = kb + ((size_t)(ks * 4 + lk) * 128 + wc * 64 + n * 16 + lr) * 8;
      bf16x8 bh_ = ldfrag(Khi + off);
      bf16x8 bl_ = ldfrag(Klo + off);
      #pragma unroll
      for (int m = 0; m < 4; ++m) {
        MFMA(acc[m][n], ah[m], bh_);
        MFMA(acc[m][n], ah[m], bl_);
        MFMA(acc[m][n], al[m], bh_);
      }
    }
  }
  for (int i = tid; i < 128 * 129; i += 256) ((float*)W)[i] = 0.f;
  #pragma unroll
  for (int m = 0; m < 4; ++m)
    #pragma unroll
    for (int n = 0; n < 4; ++n)
      #pragma unroll
      for (int q = 0; q < 4; ++q) {
        const int row = wr * 64 + m * 16 + lk * 4 + q;
        const int col = wc * 64 + n * 16 + lr;
        float v = __expf(acc[m][n][q] * 0.0625f);
        if (row == col) v += 1e-5f;
        L[row][col] = v;
      }
  __syncthreads();
  if (tid < 128) {
    const int c = tid;
    W[c][c] = 1.f / L[c][c];
    for (int r = c + 1; r < 128; ++r) {
      float s0 = 0.f, s1 = 0.f, s2 = 0.f, s3 = 0.f;
      int j = c;
      for (; j + 4 <= r; j += 4) {
        s0 += L[r][j]     * W[j][c];
        s1 += L[r][j + 1] * W[j + 1][c];
        s2 += L[r][j + 2] * W[j + 2][c];
        s3 += L[r][j + 3] * W[j + 3][c];
      }
      for (; j < r; ++j) s0 += L[r][j] * W[j][c];
      W[r][c] = -((s0 + s1) + (s2 + s3)) / L[r][r];
    }
  }
  __syncthreads();
  const size_t wb = (size_t)(bh * 16 + t) * 16384;
  for (int i = tid; i < 2048; i += 256) {
    const int kc = i >> 7, r = i & 127;
    ushort oh[8], ol[8];
    #pragma unroll
    for (int j = 0; j < 8; ++j) split2(W[r][kc * 8 + j], oh[j], ol[j]);
    *(i32x4*)(Whi + wb + (size_t)i * 8) = *(i32x4*)oh;
    *(i32x4*)(Wlo + wb + (size_t)i * 8) = *(i32x4*)ol;
  }
}

// ---------------------------------------------------------------------------
// apply_w0: sol_0 = W_0 @ V_0 (split-MFMA, in place on V), 512 thr (2x4 waves).
// Grid (4 colchunk, 8 bh): block handles ONE 128-col chunk cc = blockIdx.x.
// Also writes sol_0 split B-pack (coalesced layout) into Sroll slot 0.
// ---------------------------------------------------------------------------
__global__ __launch_bounds__(512) void apply_w0_kernel(
    const ushort* __restrict__ Whi, const ushort* __restrict__ Wlo,
    float* __restrict__ V, ushort* __restrict__ SR)
{
  __shared__ __align__(16) ushort shi[16 * 128 * 8];   // 32 KB
  __shared__ __align__(16) ushort slo[16 * 128 * 8];   // 32 KB
  const int cc = blockIdx.x, bh = blockIdx.y;
  const int b = bh >> 2, h = bh & 3;
  const int tid = threadIdx.x;
  const int lane = tid & 63, w = tid >> 6;
  const int wr = w >> 2, wc = w & 3, lr = lane & 15, lk = lane >> 4;
  const size_t wb = (size_t)(bh * 16) * 16384;
  float* Vrows = V + (size_t)b * SEQ * LDV + h * 512;
  ushort* srw = SR + (size_t)bh * 131072;   // slot 0

  {
    const int k = tid >> 2, c0 = (tid & 3) * 32;
    const float* vp = Vrows + (size_t)k * LDV + cc * 128 + c0;
    for (int c = 0; c < 32; ++c) {
      ushort hi, lo;
      split2(vp[c], hi, lo);
      const int idx = (((k >> 3) * 128) + c0 + c) * 8 + (k & 7);
      shi[idx] = hi; slo[idx] = lo;
    }
  }
  __syncthreads();
  f32x4 acc[4][2];
  #pragma unroll
  for (int i = 0; i < 4; ++i)
    #pragma unroll
    for (int j = 0; j < 2; ++j) acc[i][j] = (f32x4)(0.f);
  #pragma unroll
  for (int ks = 0; ks < 4; ++ks) {
    bf16x8 ah[4], al[4];
    #pragma unroll
    for (int m = 0; m < 4; ++m) {
      const size_t off = wb + ((size_t)(ks * 4 + lk) * 128 + wr * 64 + m * 16 + lr) * 8;
      ah[m] = ldfrag(Whi + off);
      al[m] = ldfrag(Wlo + off);
    }
    #pragma unroll
    for (int n = 0; n < 2; ++n) {
      const int idx = (((ks * 4 + lk) * 128) + wc * 32 + n * 16 + lr) * 8;
      bf16x8 bh_ = ldfrag(&shi[idx]);
      bf16x8 bl_ = ldfrag(&slo[idx]);
      #pragma unroll
      for (int m = 0; m < 4; ++m) {
        MFMA(acc[m][n], ah[m], bh_);
        MFMA(acc[m][n], ah[m], bl_);
        MFMA(acc[m][n], al[m], bh_);
      }
    }
  }
  #pragma unroll
  for (int m = 0; m < 4; ++m)
    #pragma unroll
    for (int n = 0; n < 2; ++n) {
      const int col = wc * 32 + n * 16 + lr;
      #pragma unroll
      for (int q = 0; q < 4; ++q) {
        const int row = wr * 64 + m * 16 + lk * 4 + q;
        const float v = acc[m][n][q];
        Vrows[(size_t)row * LDV + cc * 128 + col] = v;
        ushort hi, lo;
        split2(v, hi, lo);
        const size_t so = ((size_t)(row >> 3) * 512 + cc * 128 + col) * 8 + (row & 7);
        srw[so] = hi; srw[65536 + so] = lo;
      }
    }
}

// ---------------------------------------------------------------------------
// solve_step(t): trailing blocks ib > t:  V_ib -= exp(K_ib K_t^T/16) @ sol_t
// (split-bf16 MFMA; sol_t fragments from coalesced Sroll slot t&1).
// Lead block (ib == t+1) then applies W_{t+1} producing sol_{t+1} in place
// + split B-pack into Sroll slot (t+1)&1.   512 thr (2x4 waves).
// Grid (15-t, 4 colchunk, 8 bh): block handles ONE cc = blockIdx.y.
// Lead reuses the pA LDS buffers for rhs staging -> LDS 64KB, 2 blocks/CU.
// ---------------------------------------------------------------------------
__global__ __launch_bounds__(512) void solve_step_kernel(
    const ushort* __restrict__ Khi, const ushort* __restrict__ Klo,
    const ushort* __restrict__ Whi, const ushort* __restrict__ Wlo,
    float* __restrict__ V, ushort* __restrict__ SR, int t)
{
  __shared__ __align__(16) ushort pAhi[16 * 128 * 8];   // 32 KB
  __shared__ __align__(16) ushort pAlo[16 * 128 * 8];   // 32 KB
  const int ib = t + 1 + blockIdx.x;
  const int cc = blockIdx.y;
  const int bh = blockIdx.z;
  const int b = bh >> 2, h = bh & 3;
  const bool lead = (blockIdx.x == 0);
  const int tid = threadIdx.x;
  const int lane = tid & 63, w = tid >> 6;
  const int wr = w >> 2, wc = w & 3, lr = lane & 15, lk = lane >> 4;
  const size_t kbi = (size_t)(bh * 16 + ib) * 32768;
  const size_t kbt = (size_t)(bh * 16 + t) * 32768;
  float* Vhead = V + (size_t)b * SEQ * LDV + h * 512;
  float* Vib = Vhead + (size_t)ib * 128 * LDV;
  const ushort* srr = SR + (size_t)(t & 1) * 1048576 + (size_t)bh * 131072;
  ushort* srw       = SR + (size_t)((t + 1) & 1) * 1048576 + (size_t)bh * 131072;

  // Phase A: S = exp(K_ib K_t^T / 16) -> split A-pack (k = t-row index)
  {
    f32x4 a1[4][2];
    #pragma unroll
    for (int i = 0; i < 4; ++i)
      #pragma unroll
      for (int j = 0; j < 2; ++j) a1[i][j] = (f32x4)(0.f);
    #pragma unroll
    for (int ks = 0; ks < 8; ++ks) {
      bf16x8 ah[4], al[4];
      #pragma unroll
      for (int m = 0; m < 4; ++m) {
        const size_t off = kbi + ((size_t)(ks * 4 + lk) * 128 + wr * 64 + m * 16 + lr) * 8;
        ah[m] = ldfrag(Khi + off);
        al[m] = ldfrag(Klo + off);
      }
      #pragma unroll
      for (int n = 0; n < 2; ++n) {
        const size_t off = kbt + ((size_t)(ks * 4 + lk) * 128 + wc * 32 + n * 16 + lr) * 8;
        bf16x8 bh_ = ldfrag(Khi + off);
        bf16x8 bl_ = ldfrag(Klo + off);
        #pragma unroll
        for (int m = 0; m < 4; ++m) {
          MFMA(a1[m][n], ah[m], bh_);
          MFMA(a1[m][n], ah[m], bl_);
          MFMA(a1[m][n], al[m], bh_);
        }
      }
    }
    #pragma unroll
    for (int m = 0; m < 4; ++m)
      #pragma unroll
      for (int n = 0; n < 2; ++n)
        #pragma unroll
        for (int q = 0; q < 4; ++q) {
          const int row = wr * 64 + m * 16 + lk * 4 + q;
          const int c   = wc * 32 + n * 16 + lr;
          const float e = __expf(a1[m][n][q] * 0.0625f);
          ushort hi, lo;
          split2(e, hi, lo);
          const int idx = (((c >> 3) * 128) + row) * 8 + (c & 7);
          pAhi[idx] = hi; pAlo[idx] = lo;
        }
  }
  __syncthreads();

  // PV: u = S @ sol_t (cc chunk)
  f32x4 u[4][2];
  #pragma unroll
  for (int i = 0; i < 4; ++i)
    #pragma unroll
    for (int j = 0; j < 2; ++j) u[i][j] = (f32x4)(0.f);
  #pragma unroll
  for (int ks = 0; ks < 4; ++ks) {
    bf16x8 ah[4], al[4];
    #pragma unroll
    for (int m = 0; m < 4; ++m) {
      const int idx = (((ks * 4 + lk) * 128) + wr * 64 + m * 16 + lr) * 8;
      ah[m] = ldfrag(&pAhi[idx]);
      al[m] = ldfrag(&pAlo[idx]);
    }
    #pragma unroll
    for (int n = 0; n < 2; ++n) {
      const size_t c = cc * 128 + wc * 32 + n * 16 + lr;
      bf16x8 bh_ = ldfrag(srr + ((size_t)(ks * 4 + lk) * 512 + c) * 8);
      bf16x8 bl_ = ldfrag(srr + 65536 + ((size_t)(ks * 4 + lk) * 512 + c) * 8);
      #pragma unroll
      for (int m = 0; m < 4; ++m) {
        MFMA(u[m][n], ah[m], bh_);
        MFMA(u[m][n], ah[m], bl_);
        MFMA(u[m][n], al[m], bh_);
      }
    }
  }
  float nv[4][2][4];
  #pragma unroll
  for (int m = 0; m < 4; ++m)
    #pragma unroll
    for (int n = 0; n < 2; ++n) {
      const int col = wc * 32 + n * 16 + lr;
      #pragma unroll
      for (int q = 0; q < 4; ++q) {
        const int row = wr * 64 + m * 16 + lk * 4 + q;
        const float v = Vib[(size_t)row * LDV + cc * 128 + col] - u[m][n][q];
        nv[m][n][q] = v;
        if (!lead) Vib[(size_t)row * LDV + cc * 128 + col] = v;
      }
    }
  if (lead) {
    __syncthreads();   // all pA reads done; reuse pA buffers for rhs staging
    #pragma unroll
    for (int m = 0; m < 4; ++m)
      #pragma unroll
      for (int n = 0; n < 2; ++n) {
        const int col = wc * 32 + n * 16 + lr;
        #pragma unroll
        for (int q = 0; q < 4; ++q) {
          const int row = wr * 64 + m * 16 + lk * 4 + q;
          ushort hi, lo;
          split2(nv[m][n][q], hi, lo);
          const int idx = (((row >> 3) * 128) + col) * 8 + (row & 7);
          pAhi[idx] = hi; pAlo[idx] = lo;
        }
      }
    __syncthreads();
    f32x4 s2[4][2];
    #pragma unroll
    for (int i = 0; i < 4; ++i)
      #pragma unroll
      for (int j = 0; j < 2; ++j) s2[i][j] = (f32x4)(0.f);
    const size_t wb = (size_t)(bh * 16 + ib) * 16384;
    #pragma unroll
    for (int ks = 0; ks < 4; ++ks) {
      bf16x8 ah[4], al[4];
      #pragma unroll
      for (int m = 0; m < 4; ++m) {
        const size_t off = wb + ((size_t)(ks * 4 + lk) * 128 + wr * 64 + m * 16 + lr) * 8;
        ah[m] = ldfrag(Whi + off);
        al[m] = ldfrag(Wlo + off);
      }
      #pragma unroll
      for (int n = 0; n < 2; ++n) {
        const int idx = (((ks * 4 + lk) * 128) + wc * 32 + n * 16 + lr) * 8;
        bf16x8 bh_ = ldfrag(&pAhi[idx]);
        bf16x8 bl_ = ldfrag(&pAlo[idx]);
        #pragma unroll
        for (int m = 0; m < 4; ++m) {
          MFMA(s2[m][n], ah[m], bh_);
          MFMA(s2[m][n], ah[m], bl_);
          MFMA(s2[m][n], al[m], bh_);
        }
      }
    }
    #pragma unroll
    for (int m = 0; m < 4; ++m)
      #pragma unroll
      for (int n = 0; n < 2; ++n) {
        const int col = wc * 32 + n * 16 + lr;
        #pragma unroll
        for (int q = 0; q < 4; ++q) {
          const int row = wr * 64 + m * 16 + lk * 4 + q;
          const float v = s2[m][n][q];
          Vib[(size_t)row * LDV + cc * 128 + col] = v;
          ushort hi, lo;
          split2(v, hi, lo);
          const size_t so = ((size_t)(row >> 3) * 512 + cc * 128 + col) * 8 + (row & 7);
          srw[so] = hi; srw[65536 + so] = lo;
        }
      }
  }
}

// ---------------------------------------------------------------------------
// o_kernel v5: O = tril(exp(Q K^T/16)) @ sol.
// Grid = 1024 blocks x 256 thr (4 waves): bid = bh(8, fastest -> XCD spread)
// | rh(4 x 32-row quarters) | cq(4 x 128-col quarters) | p(8 pair index).
// Each block runs tasks ib = p and ib = 15-p sequentially -> UNIFORM weight
// 17 jb-units per block (fixes the 1.9x load-imbalance makespan of v4).
// Per jb: 32x128 Gram (dup 4x via cq), P double-buffered (2 x 16KB LDS,
// one barrier per jb), PV 32x128. 4 blocks/CU; setprio around MFMA.
// ---------------------------------------------------------------------------
__global__ __launch_bounds__(256, 4) void o_kernel(
    const ushort* __restrict__ Qhi, const ushort* __restrict__ Qlo,
    const ushort* __restrict__ Khi, const ushort* __restrict__ Klo,
    const ushort* __restrict__ Sp0, const ushort* __restrict__ Sp1,
    ushort* __restrict__ Opack)
{
  __shared__ __align__(16) ushort Phi_s[2][16 * 32 * 8];  // 2 x 8 KB
  __shared__ __align__(16) ushort Plo_s[2][16 * 32 * 8];  // 2 x 8 KB
  const int bid = blockIdx.x;
  const int bh  = bid & 7;
  const int rh  = (bid >> 3) & 3;     // 32-row quarter of the ib block
  const int cq  = (bid >> 5) & 3;     // 128-col quarter of the head's 512
  const int p   = bid >> 7;           // 0..7 pair index
  const int b = bh >> 2, h = bh & 3;
  const int tid = threadIdx.x;
  const int lane = tid & 63;
  const int wv = tid >> 6;            // 0..3
  const int lr = lane & 15, lk = lane >> 4;
  const ushort* Spb = b ? Sp1 : Sp0;

  int pb = 0;
  #pragma unroll
  for (int task = 0; task < 2; ++task) {
    const int ib = task ? (15 - p) : p;
    const size_t qb = (size_t)(bh * 16 + ib) * 32768;
    f32x4 acc[2][2];
    #pragma unroll
    for (int i = 0; i < 2; ++i)
      #pragma unroll
      for (int j = 0; j < 2; ++j) acc[i][j] = (f32x4)(0.f);

    for (int jb = 0; jb <= ib; ++jb) {
      // Gram: s = Q_ib[rh quarter, 32 rows] . K_jb^T (split, 3-term) -> 32x128
      f32x4 s1[2][2];
      #pragma unroll
      for (int i = 0; i < 2; ++i)
        #pragma unroll
        for (int j = 0; j < 2; ++j) s1[i][j] = (f32x4)(0.f);
      const size_t kb = (size_t)(bh * 16 + jb) * 32768;
      __builtin_amdgcn_s_setprio(1);
      #pragma unroll
      for (int ks = 0; ks < 8; ++ks) {
        bf16x8 ah[2], al[2];
        #pragma unroll
        for (int m = 0; m < 2; ++m) {
          const size_t off = qb + ((size_t)(ks * 4 + lk) * 128 + rh * 32 + m * 16 + lr) * 8;
          ah[m] = ldfrag(Qhi + off);
          al[m] = ldfrag(Qlo + off);
        }
        #pragma unroll
        for (int n = 0; n < 2; ++n) {
          const size_t off = kb + ((size_t)(ks * 4 + lk) * 128 + wv * 32 + n * 16 + lr) * 8;
          bf16x8 bh_ = ldfrag(Khi + off);
          bf16x8 bl_ = ldfrag(Klo + off);
          #pragma unroll
          for (int m = 0; m < 2; ++m) {
            MFMA(s1[m][n], ah[m], bh_);
            MFMA(s1[m][n], ah[m], bl_);
            MFMA(s1[m][n], al[m], bh_);
          }
        }
      }
      __builtin_amdgcn_s_setprio(0);
      // P = exp(s/16), tril-masked on diagonal block; split into buffer pb.
      // (buffer pb^1 may still have readers -> no barrier needed here)
      #pragma unroll
      for (int m = 0; m < 2; ++m)
        #pragma unroll
        for (int n = 0; n < 2; ++n)
          #pragma unroll
          for (int q = 0; q < 4; ++q) {
            const int rloc = m * 16 + lk * 4 + q;        // 0..31
            const int c    = wv * 32 + n * 16 + lr;      // 0..127
            float e = __expf(s1[m][n][q] * 0.0625f);
            if (jb == ib && c > rh * 32 + rloc) e = 0.f;
            ushort hi, lo;
            split2(e, hi, lo);
            const int idx = (((c >> 3) * 32) + rloc) * 8 + (c & 7);
            Phi_s[pb][idx] = hi; Plo_s[pb][idx] = lo;
          }
      __syncthreads();   // single barrier per jb: P[pb] visible to all waves
      // acc += P @ sol (split, 3-term); sol fragments from global Spack
      const ushort* sjb = Spb + ((size_t)(h * 16 + jb) * 2) * 65536;
      __builtin_amdgcn_s_setprio(1);
      #pragma unroll
      for (int ks = 0; ks < 4; ++ks) {
        bf16x8 ah[2], al[2];
        #pragma unroll
        for (int m = 0; m < 2; ++m) {
          const int idx = (((ks * 4 + lk) * 32) + m * 16 + lr) * 8;
          ah[m] = ldfrag(&Phi_s[pb][idx]);
          al[m] = ldfrag(&Plo_s[pb][idx]);
        }
        #pragma unroll
        for (int n = 0; n < 2; ++n) {
          const size_t c = cq * 128 + wv * 32 + n * 16 + lr;
          bf16x8 bh_ = ldfrag(sjb + ((size_t)(ks * 4 + lk) * 512 + c) * 8);
          bf16x8 bl_ = ldfrag(sjb + 65536 + ((size_t)(ks * 4 + lk) * 512 + c) * 8);
          #pragma unroll
          for (int m = 0; m < 2; ++m) {
            MFMA(acc[m][n], ah[m], bh_);
            MFMA(acc[m][n], ah[m], bl_);
            MFMA(acc[m][n], al[m], bh_);
          }
        }
      }
      __builtin_amdgcn_s_setprio(0);
      pb ^= 1;
    }
    // write Opack (bf16 A-pack over the 2048 O-cols, K8 = 256)
    const int row_blk = b * 16 + ib;
    #pragma unroll
    for (int m = 0; m < 2; ++m)
      #pragma unroll
      for (int n = 0; n < 2; ++n) {
        const int col = h * 512 + cq * 128 + wv * 32 + n * 16 + lr;
        #pragma unroll
        for (int q = 0; q < 4; ++q) {
          const int row = rh * 32 + m * 16 + lk * 4 + q;
          Opack[((size_t)row_blk * 256 + (col >> 3)) * 1024 + row * 8 + (col & 7)] =
              f2bf(acc[m][n][q]);
        }
      }
  }
}

// ---------------------------------------------------------------------------
extern "C" void kernel_launch(void* const* d_in, const int* in_sizes, int n_in,
                              void* d_out, int out_size, void* d_ws, size_t ws_size,
                              hipStream_t stream)
{
  const float* x  = (const float*)d_in[0];
  const float* Wq = (const float*)d_in[1];
  const float* Wk = (const float*)d_in[2];
  const float* Wv = (const float*)d_in[3];
  const float* Wo = (const float*)d_in[4];
  float* out = (float*)d_out;

  // Workspace (84 MB), phase-aliased:
  //  [0,16):  xpack(8) + Wqp/Wkp/Wvp(8)  ->  Qhi(8) + Qlo(8)
  //  [16,20): Wop (alive till end)
  //  [20,36): Q fp32  ->  Khi(8) + Klo(8)   (K pack AFTER Q pack consumed Q)
  //  [36,52): K fp32  ->  Whi(4)@36 + Wlo(4)@40 + Sroll(4)@44  ->  Spack1(16)@36
  //  [52,84): V fp32  ->  Opack(16)@52 + Spack0(16)@68
  char* base = (char*)d_ws;
  ushort* xpack = (ushort*)(base);
  ushort* Wqp   = (ushort*)(base + (8u  << 20));
  ushort* Wkp   = (ushort*)(base + (10u << 20));
  ushort* Wvp   = (ushort*)(base + (12u << 20));
  ushort* Wop   = (ushort*)(base + (16u << 20));
  float*  Q     = (float*) (base + (20u << 20));
  float*  K     = (float*) (base + (36u << 20));
  float*  V     = (float*) (base + (52u << 20));
  ushort* Qhi   = (ushort*)(base);
  ushort* Qlo   = (ushort*)(base + (8u  << 20));
  ushort* Khi   = (ushort*)(base + (20u << 20));
  ushort* Klo   = (ushort*)(base + (28u << 20));
  ushort* Whi   = (ushort*)(base + (36u << 20));
  ushort* Wlo   = (ushort*)(base + (40u << 20));
  ushort* SR    = (ushort*)(base + (44u << 20));   // Sroll, 2 slots x 2MB
  ushort* Sp1   = (ushort*)(base + (36u << 20));   // sol B-pack, batch 1
  ushort* Sp0   = (ushort*)(base + (68u << 20));   // sol B-pack, batch 0
  ushort* Opack = (ushort*)(base + (52u << 20));

  // Pack inputs
  pack_x_kernel<<<(NROW * 128) / 256, 256, 0, stream>>>(x, xpack);
  pack_w_kernel<<<(1024 * 1024 / 8) / 256, 256, 0, stream>>>(Wq, Wqp, 1024, 1024);
  pack_w_kernel<<<(1024 * 1024 / 8) / 256, 256, 0, stream>>>(Wk, Wkp, 1024, 1024);
  pack_w_kernel<<<(1024 * 2048 / 8) / 256, 256, 0, stream>>>(Wv, Wvp, 1024, 2048);
  pack_w_kernel<<<(2048 * 1024 / 8) / 256, 256, 0, stream>>>(Wo, Wop, 2048, 1024);

  // Projections (bf16 MFMA, fp32 out)
  gemm_bf16<<<dim3(DM / 128, NROW / 128), 256, 0, stream>>>(xpack, Wqp, Q, NROW, DM, DM);
  gemm_bf16<<<dim3(DM / 128, NROW / 128), 256, 0, stream>>>(xpack, Wkp, K, NROW, DM, DM);
  gemm_bf16<<<dim3(LDV / 128, NROW / 128), 256, 0, stream>>>(xpack, Wvp, V, NROW, LDV, DM);

  // Fused RoPE + split-pack: Q first (dest doesn't alias), then K (dest
  // reuses the Q fp32 region, dead after the first launch).
  rope_pack1_kernel<<<(NROW * 4 * 32) / 256, 256, 0, stream>>>(Q, Qhi, Qlo);
  rope_pack1_kernel<<<(NROW * 4 * 32) / 256, 256, 0, stream>>>(K, Khi, Klo);

  // Diagonal-block inverses, then the 16-step split-MFMA solve (in place on V)
  winv_kernel<<<dim3(NBLK, 8), 256, 0, stream>>>(Khi, Klo, Whi, Wlo);
  apply_w0_kernel<<<dim3(4, 8), 512, 0, stream>>>(Whi, Wlo, V, SR);
  for (int t = 0; t < NBLK - 1; ++t)
    solve_step_kernel<<<dim3(NBLK - 1 - t, 4, 8), 512, 0, stream>>>(Khi, Klo, Whi, Wlo, V, SR, t);

  // Pack sol to split B-packs (alias-safe ordering: b=1 first, then b=0)
  pack_sol_kernel<<<dim3(64, 2), 256, 0, stream>>>(V + (size_t)SEQ * LDV, Sp1);
  pack_sol_kernel<<<dim3(64, 2), 256, 0, stream>>>(V, Sp0);

  // O = tril(exp(QK^T/16)) @ sol  -> bf16 Opack
  o_kernel<<<1024, 256, 0, stream>>>(Qhi, Qlo, Khi, Klo, Sp0, Sp1, Opack);

  // out = O @ Wo (bf16 MFMA)
  gemm_bf16<<<dim3(DM / 128, NROW / 128), 256, 0, stream>>>(Opack, Wop, out, NROW, DM, LDV);
}

// Round 17
// 1265.577 us; speedup vs baseline: 1.1429x; 1.1429x over previous
//
#include <hip/hip_runtime.h>
#include <hip/hip_bf16.h>
#include <math.h>

// Problem constants
#define SEQ   2048
#define NROW  4096            // B*SEQ
#define DM    1024
#define LDQ   1024            // Q/K row stride (4 heads * 256)
#define LDV   2048            // V/O row stride (4 heads * 512)
#define NBLK  16              // 2048 / 128 row blocks per (b,h)

typedef float  f32x4  __attribute__((ext_vector_type(4)));
typedef int    i32x4  __attribute__((ext_vector_type(4)));
typedef __bf16 bf16x8 __attribute__((ext_vector_type(8)));

// Compiler-managed MFMA: hazards/NOPs/spills handled by the backend.
#define MFMA(d, a, b) (d) = __builtin_amdgcn_mfma_f32_16x16x32_bf16((a), (b), (d), 0, 0, 0)

__device__ inline ushort f2bf(float f) {
  __hip_bfloat16 h = __float2bfloat16(f);
  return *(ushort*)&h;
}
__device__ inline float bf2f(ushort u) {
  return __uint_as_float((unsigned)u << 16);
}
// v ~= bf2f(hi) + bf2f(lo), residual ~ 2^-18 * |v|
__device__ inline void split2(float v, ushort& hi, ushort& lo) {
  hi = f2bf(v);
  lo = f2bf(v - bf2f(hi));
}
__device__ inline bf16x8 ldfrag(const ushort* p) { return *(const bf16x8*)p; }

// Async global->LDS, 16B per lane. Both sides are linear in lane order here
// (dest byte offset = wave_base + lane*16), matching the HW's linear write.
__device__ inline void gload_lds16(const ushort* g, ushort* l) {
  __builtin_amdgcn_global_load_lds(
      (const __attribute__((address_space(1))) void*)g,
      (__attribute__((address_space(3))) void*)l, 16, 0, 0);
}

// ---------------------------------------------------------------------------
// Packing kernels (bf16 "k-chunk-major" MFMA operand layout):
// pack[blk][kc][r][8] holds element with k = kc*8+j  (16B-contiguous rows).
// ---------------------------------------------------------------------------
__global__ void pack_x_kernel(const float* __restrict__ X, ushort* __restrict__ P)
{
  const int t = blockIdx.x * 256 + threadIdx.x;   // < 4096*128
  const int kc = t & 127;
  const int m  = t >> 7;
  const float* src = X + (size_t)m * DM + kc * 8;
  f32x4 v0 = *(const f32x4*)src;
  f32x4 v1 = *(const f32x4*)(src + 4);
  ushort o[8];
  #pragma unroll
  for (int j = 0; j < 4; ++j) { o[j] = f2bf(v0[j]); o[4 + j] = f2bf(v1[j]); }
  ushort* dst = P + ((size_t)((m >> 7) * 128 + kc) * 128 + (m & 127)) * 8;
  *(i32x4*)dst = *(i32x4*)o;
}

__global__ void pack_w_kernel(const float* __restrict__ W, ushort* __restrict__ P,
                              int K, int N)
{
  const int K8 = K >> 3;
  const int t = blockIdx.x * 256 + threadIdx.x;   // < N*K/8
  const int c  = t & 127;
  const int kc = (t >> 7) % K8;
  const int nb = t / (128 * K8);
  ushort o[8];
  #pragma unroll
  for (int j = 0; j < 8; ++j)
    o[j] = f2bf(W[(size_t)(kc * 8 + j) * N + nb * 128 + c]);
  ushort* dst = P + ((size_t)(nb * K8 + kc) * 128 + c) * 8;
  *(i32x4*)dst = *(i32x4*)o;
}

// Fused Wq+Wk pack (both 1024x1024): blockIdx.y selects source/dest.
__global__ void pack_w2_kernel(const float* __restrict__ Wq, const float* __restrict__ Wk,
                               ushort* __restrict__ Pq, ushort* __restrict__ Pk)
{
  const float* W = blockIdx.y ? Wk : Wq;
  ushort* P      = blockIdx.y ? Pk : Pq;
  const int K8 = 128;
  const int t = blockIdx.x * 256 + threadIdx.x;   // < 1024*128
  const int c  = t & 127;
  const int kc = (t >> 7) % K8;
  const int nb = t / (128 * K8);
  ushort o[8];
  #pragma unroll
  for (int j = 0; j < 8; ++j)
    o[j] = f2bf(W[(size_t)(kc * 8 + j) * 1024 + nb * 128 + c]);
  ushort* dst = P + ((size_t)(nb * K8 + kc) * 128 + c) * 8;
  *(i32x4*)dst = *(i32x4*)o;
}

// ---------------------------------------------------------------------------
// Fused RoPE + split-pack for ONE matrix (launched once for Q, once for K,
// in that order -- the K launch's destination aliases the dead Q fp32 buffer,
// which is only safe because the Q launch completed first).
// ---------------------------------------------------------------------------
__global__ void rope_pack1_kernel(const float* __restrict__ M,
                                  ushort* __restrict__ Phi, ushort* __restrict__ Plo)
{
  const int idx = blockIdx.x * 256 + threadIdx.x;  // < 4096*4*32
  const int g   = idx & 31;           // d-group (8 elements)
  const int h   = (idx >> 5) & 3;
  const int row = idx >> 7;           // 0..4095
  const int pos = row & (SEQ - 1);
  const int d0  = g * 8;
  const bool hihalf = d0 >= 128;
  const int f0 = d0 & 127;
  const float* mp = M + (size_t)row * LDQ + h * 256;
  ushort oh[8], ol[8];
  #pragma unroll
  for (int j = 0; j < 8; ++j) {
    const int f = f0 + j;
    const float inv = expf(-(float)f * (9.210340371976184f / 128.f));
    float s, c;
    sincosf((float)pos * inv, &s, &c);
    const float m1 = mp[f], m2 = mp[f + 128];
    const float mv = hihalf ? (m2 * c + m1 * s) : (m1 * c - m2 * s);
    split2(mv, oh[j], ol[j]);
  }
  const int b = row >> 11, r = row & 127, tb = (row & 2047) >> 7;
  const int bh = b * 4 + h;
  const size_t doff = (((size_t)(bh * 16 + tb) * 32 + g) * 128 + r) * 8;
  *(i32x4*)(Phi + doff) = *(i32x4*)oh;
  *(i32x4*)(Plo + doff) = *(i32x4*)ol;
}

// sol (fp32, one batch's 2048 rows of V) -> split B-pack, COALESCED layout:
// Sp[(h*16+jb)*2 + hl][kc 0..15][c 0..511][8]
__global__ void pack_sol_kernel(const float* __restrict__ Vb, ushort* __restrict__ Sp)
{
  const int hj = blockIdx.x;                         // h*16 + jb
  const int h  = hj >> 4, jb = hj & 15;
  const int c  = blockIdx.y * 256 + threadIdx.x;     // 0..511
  const float* src = Vb + (size_t)(jb * 128) * LDV + h * 512 + c;
  ushort* dhi = Sp + ((size_t)hj * 2    ) * 65536;
  ushort* dlo = Sp + ((size_t)hj * 2 + 1) * 65536;
  for (int kc = 0; kc < 16; ++kc) {
    ushort oh[8], ol[8];
    #pragma unroll
    for (int j = 0; j < 8; ++j)
      split2(src[(size_t)(kc * 8 + j) * LDV], oh[j], ol[j]);
    *(i32x4*)(dhi + ((size_t)kc * 512 + c) * 8) = *(i32x4*)oh;
    *(i32x4*)(dlo + ((size_t)kc * 512 + c) * 8) = *(i32x4*)ol;
  }
}

// ---------------------------------------------------------------------------
// bf16 MFMA GEMM: C[M,N] fp32 = Apack * Bpack. 128x128 tile, 4 waves 2x2.
// Staging via async global_load_lds (16B/lane, linear both sides).
// ---------------------------------------------------------------------------
__global__ __launch_bounds__(256) void gemm_bf16(
    const ushort* __restrict__ Ap, const ushort* __restrict__ Bp,
    float* __restrict__ C, int M, int N, int K)
{
  __shared__ __align__(16) ushort a_lds[8][128][8];
  __shared__ __align__(16) ushort b_lds[8][128][8];
  const int tid  = threadIdx.x;
  const int lane = tid & 63;
  const int w    = tid >> 6;
  const int wr   = w >> 1, wc = w & 1;
  const int mb = blockIdx.y, nb = blockIdx.x;
  const int K8 = K >> 3;
  const ushort* aT = Ap + (size_t)mb * K8 * 1024;
  const ushort* bT = Bp + (size_t)nb * K8 * 1024;
  const int lr = lane & 15;
  const int lk = lane >> 4;

  f32x4 acc[4][4];
  #pragma unroll
  for (int i = 0; i < 4; ++i)
    #pragma unroll
    for (int j = 0; j < 4; ++j) acc[i][j] = (f32x4)(0.f);

  for (int kc0 = 0; kc0 < K8; kc0 += 8) {
    const ushort* asrc = aT + (size_t)kc0 * 1024;
    const ushort* bsrc = bT + (size_t)kc0 * 1024;
    __syncthreads();   // previous iteration's LDS reads complete
    #pragma unroll
    for (int it = 0; it < 4; ++it) {
      gload_lds16(asrc + it * 2048 + tid * 8, ((ushort*)a_lds) + it * 2048 + tid * 8);
      gload_lds16(bsrc + it * 2048 + tid * 8, ((ushort*)b_lds) + it * 2048 + tid * 8);
    }
    __syncthreads();   // vmcnt drained by compiler before barrier
    #pragma unroll
    for (int kk = 0; kk < 2; ++kk) {
      bf16x8 af[4], bf[4];
      #pragma unroll
      for (int m = 0; m < 4; ++m)
        af[m] = ldfrag(&a_lds[kk * 4 + lk][wr * 64 + m * 16 + lr][0]);
      #pragma unroll
      for (int n = 0; n < 4; ++n)
        bf[n] = ldfrag(&b_lds[kk * 4 + lk][wc * 64 + n * 16 + lr][0]);
      #pragma unroll
      for (int m = 0; m < 4; ++m)
        #pragma unroll
        for (int n = 0; n < 4; ++n)
          MFMA(acc[m][n], af[m], bf[n]);
    }
  }
  const int r0 = (lane >> 4) * 4;
  #pragma unroll
  for (int m = 0; m < 4; ++m)
    #pragma unroll
    for (int n = 0; n < 4; ++n) {
      const int row = mb * 128 + wr * 64 + m * 16 + r0;
      const int col = nb * 128 + wc * 64 + n * 16 + lr;
      float* cp = C + (size_t)row * N + col;
      #pragma unroll
      for (int q = 0; q < 4; ++q) cp[(size_t)q * N] = acc[m][n][q];
    }
}

// ---------------------------------------------------------------------------
// winv: L = tril(exp(K_t K_t^T/16)) + eps*I via split-MFMA Gram, fp32 invert,
// store W = L^-1 as SPLIT bf16 A-packs (Whi + Wlo). (256 thr, 2x2 waves)
// ---------------------------------------------------------------------------
__global__ __launch_bounds__(256) void winv_kernel(
    const ushort* __restrict__ Khi, const ushort* __restrict__ Klo,
    ushort* __restrict__ Whi, ushort* __restrict__ Wlo)
{
  __shared__ float L[128][129];
  __shared__ float W[128][129];
  const int t = blockIdx.x, bh = blockIdx.y;
  const int tid = threadIdx.x;
  const int lane = tid & 63, w = tid >> 6;
  const int wr = w >> 1, wc = w & 1;
  const int lr = lane & 15, lk = lane >> 4;
  const size_t kb = (size_t)(bh * 16 + t) * 32768;

  f32x4 acc[4][4];
  #pragma unroll
  for (int i = 0; i < 4; ++i)
    #pragma unroll
    for (int j = 0; j < 4; ++j) acc[i][j] = (f32x4)(0.f);
  #pragma unroll
  for (int ks = 0; ks < 8; ++ks) {
    bf16x8 ah[4], al[4];
    #pragma unroll
    for (int m = 0; m < 4; ++m) {
      const size_t off = kb + ((size_t)(ks * 4 + lk) * 128 + wr * 64 + m * 16 + lr) * 8;
      ah[m] = ldfrag(Khi + off);
      al[m] = ldfrag(Klo + off);
    }
    #pragma unroll
    for (int n = 0; n < 4; ++n) {
      const size_t off = kb + ((size_t)(ks * 4 + lk) * 128 + wc * 64 + n * 16 + lr) * 8;
      bf16x8 bh_ = ldfrag(Khi + off);
      bf16x8 bl_ = ldfrag(Klo + off);
      #pragma unroll
      for (int m = 0; m < 4; ++m) {
        MFMA(acc[m][n], ah[m], bh_);
        MFMA(acc[m][n], ah[m], bl_);
        MFMA(acc[m][n], al[m], bh_);
      }
    }
  }
  for (int i = tid; i < 128 * 129; i += 256) ((float*)W)[i] = 0.f;
  #pragma unroll
  for (int m = 0; m < 4; ++m)
    #pragma unroll
    for (int n = 0; n < 4; ++n)
      #pragma unroll
      for (int q = 0; q < 4; ++q) {
        const int row = wr * 64 + m * 16 + lk * 4 + q;
        const int col = wc * 64 + n * 16 + lr;
        float v = __expf(acc[m][n][q] * 0.0625f);
        if (row == col) v += 1e-5f;
        L[row][col] = v;
      }
  __syncthreads();
  if (tid < 128) {
    const int c = tid;
    W[c][c] = 1.f / L[c][c];
    for (int r = c + 1; r < 128; ++r) {
      float s0 = 0.f, s1 = 0.f, s2 = 0.f, s3 = 0.f;
      int j = c;
      for (; j + 4 <= r; j += 4) {
        s0 += L[r][j]     * W[j][c];
        s1 += L[r][j + 1] * W[j + 1][c];
        s2 += L[r][j + 2] * W[j + 2][c];
        s3 += L[r][j + 3] * W[j + 3][c];
      }
      for (; j < r; ++j) s0 += L[r][j] * W[j][c];
      W[r][c] = -((s0 + s1) + (s2 + s3)) / L[r][r];
    }
  }
  __syncthreads();
  const size_t wb = (size_t)(bh * 16 + t) * 16384;
  for (int i = tid; i < 2048; i += 256) {
    const int kc = i >> 7, r = i & 127;
    ushort oh[8], ol[8];
    #pragma unroll
    for (int j = 0; j < 8; ++j) split2(W[r][kc * 8 + j], oh[j], ol[j]);
    *(i32x4*)(Whi + wb + (size_t)i * 8) = *(i32x4*)oh;
    *(i32x4*)(Wlo + wb + (size_t)i * 8) = *(i32x4*)ol;
  }
}

// ---------------------------------------------------------------------------
// apply_w0: sol_0 = W_0 @ V_0 (split-MFMA, in place on V), 512 thr (2x4 waves).
// Grid (4 colchunk, 8 bh): block handles ONE 128-col chunk cc = blockIdx.x.
// Also writes sol_0 split B-pack (coalesced layout) into Sroll slot 0.
// ---------------------------------------------------------------------------
__global__ __launch_bounds__(512) void apply_w0_kernel(
    const ushort* __restrict__ Whi, const ushort* __restrict__ Wlo,
    float* __restrict__ V, ushort* __restrict__ SR)
{
  __shared__ __align__(16) ushort shi[16 * 128 * 8];   // 32 KB
  __shared__ __align__(16) ushort slo[16 * 128 * 8];   // 32 KB
  const int cc = blockIdx.x, bh = blockIdx.y;
  const int b = bh >> 2, h = bh & 3;
  const int tid = threadIdx.x;
  const int lane = tid & 63, w = tid >> 6;
  const int wr = w >> 2, wc = w & 3, lr = lane & 15, lk = lane >> 4;
  const size_t wb = (size_t)(bh * 16) * 16384;
  float* Vrows = V + (size_t)b * SEQ * LDV + h * 512;
  ushort* srw = SR + (size_t)bh * 131072;   // slot 0

  {
    const int k = tid >> 2, c0 = (tid & 3) * 32;
    const float* vp = Vrows + (size_t)k * LDV + cc * 128 + c0;
    for (int c = 0; c < 32; ++c) {
      ushort hi, lo;
      split2(vp[c], hi, lo);
      const int idx = (((k >> 3) * 128) + c0 + c) * 8 + (k & 7);
      shi[idx] = hi; slo[idx] = lo;
    }
  }
  __syncthreads();
  f32x4 acc[4][2];
  #pragma unroll
  for (int i = 0; i < 4; ++i)
    #pragma unroll
    for (int j = 0; j < 2; ++j) acc[i][j] = (f32x4)(0.f);
  #pragma unroll
  for (int ks = 0; ks < 4; ++ks) {
    bf16x8 ah[4], al[4];
    #pragma unroll
    for (int m = 0; m < 4; ++m) {
      const size_t off = wb + ((size_t)(ks * 4 + lk) * 128 + wr * 64 + m * 16 + lr) * 8;
      ah[m] = ldfrag(Whi + off);
      al[m] = ldfrag(Wlo + off);
    }
    #pragma unroll
    for (int n = 0; n < 2; ++n) {
      const int idx = (((ks * 4 + lk) * 128) + wc * 32 + n * 16 + lr) * 8;
      bf16x8 bh_ = ldfrag(&shi[idx]);
      bf16x8 bl_ = ldfrag(&slo[idx]);
      #pragma unroll
      for (int m = 0; m < 4; ++m) {
        MFMA(acc[m][n], ah[m], bh_);
        MFMA(acc[m][n], ah[m], bl_);
        MFMA(acc[m][n], al[m], bh_);
      }
    }
  }
  #pragma unroll
  for (int m = 0; m < 4; ++m)
    #pragma unroll
    for (int n = 0; n < 2; ++n) {
      const int col = wc * 32 + n * 16 + lr;
      #pragma unroll
      for (int q = 0; q < 4; ++q) {
        const int row = wr * 64 + m * 16 + lk * 4 + q;
        const float v = acc[m][n][q];
        Vrows[(size_t)row * LDV + cc * 128 + col] = v;
        ushort hi, lo;
        split2(v, hi, lo);
        const size_t so = ((size_t)(row >> 3) * 512 + cc * 128 + col) * 8 + (row & 7);
        srw[so] = hi; srw[65536 + so] = lo;
      }
    }
}

// ---------------------------------------------------------------------------
// solve_step(t): trailing blocks ib > t:  V_ib -= exp(K_ib K_t^T/16) @ sol_t
// (split-bf16 MFMA; sol_t fragments from coalesced Sroll slot t&1).
// Lead block (ib == t+1) then applies W_{t+1} producing sol_{t+1} in place
// + split B-pack into Sroll slot (t+1)&1.   512 thr (2x4 waves).
// Grid (15-t, 4 colchunk, 8 bh): block handles ONE cc = blockIdx.y.
// Lead reuses the pA LDS buffers for rhs staging -> LDS 64KB, 2 blocks/CU.
// ---------------------------------------------------------------------------
__global__ __launch_bounds__(512) void solve_step_kernel(
    const ushort* __restrict__ Khi, const ushort* __restrict__ Klo,
    const ushort* __restrict__ Whi, const ushort* __restrict__ Wlo,
    float* __restrict__ V, ushort* __restrict__ SR, int t)
{
  __shared__ __align__(16) ushort pAhi[16 * 128 * 8];   // 32 KB
  __shared__ __align__(16) ushort pAlo[16 * 128 * 8];   // 32 KB
  const int ib = t + 1 + blockIdx.x;
  const int cc = blockIdx.y;
  const int bh = blockIdx.z;
  const int b = bh >> 2, h = bh & 3;
  const bool lead = (blockIdx.x == 0);
  const int tid = threadIdx.x;
  const int lane = tid & 63, w = tid >> 6;
  const int wr = w >> 2, wc = w & 3, lr = lane & 15, lk = lane >> 4;
  const size_t kbi = (size_t)(bh * 16 + ib) * 32768;
  const size_t kbt = (size_t)(bh * 16 + t) * 32768;
  float* Vhead = V + (size_t)b * SEQ * LDV + h * 512;
  float* Vib = Vhead + (size_t)ib * 128 * LDV;
  const ushort* srr = SR + (size_t)(t & 1) * 1048576 + (size_t)bh * 131072;
  ushort* srw       = SR + (size_t)((t + 1) & 1) * 1048576 + (size_t)bh * 131072;

  // Phase A: S = exp(K_ib K_t^T / 16) -> split A-pack (k = t-row index)
  {
    f32x4 a1[4][2];
    #pragma unroll
    for (int i = 0; i < 4; ++i)
      #pragma unroll
      for (int j = 0; j < 2; ++j) a1[i][j] = (f32x4)(0.f);
    #pragma unroll
    for (int ks = 0; ks < 8; ++ks) {
      bf16x8 ah[4], al[4];
      #pragma unroll
      for (int m = 0; m < 4; ++m) {
        const size_t off = kbi + ((size_t)(ks * 4 + lk) * 128 + wr * 64 + m * 16 + lr) * 8;
        ah[m] = ldfrag(Khi + off);
        al[m] = ldfrag(Klo + off);
      }
      #pragma unroll
      for (int n = 0; n < 2; ++n) {
        const size_t off = kbt + ((size_t)(ks * 4 + lk) * 128 + wc * 32 + n * 16 + lr) * 8;
        bf16x8 bh_ = ldfrag(Khi + off);
        bf16x8 bl_ = ldfrag(Klo + off);
        #pragma unroll
        for (int m = 0; m < 4; ++m) {
          MFMA(a1[m][n], ah[m], bh_);
          MFMA(a1[m][n], ah[m], bl_);
          MFMA(a1[m][n], al[m], bh_);
        }
      }
    }
    #pragma unroll
    for (int m = 0; m < 4; ++m)
      #pragma unroll
      for (int n = 0; n < 2; ++n)
        #pragma unroll
        for (int q = 0; q < 4; ++q) {
          const int row = wr * 64 + m * 16 + lk * 4 + q;
          const int c   = wc * 32 + n * 16 + lr;
          const float e = __expf(a1[m][n][q] * 0.0625f);
          ushort hi, lo;
          split2(e, hi, lo);
          const int idx = (((c >> 3) * 128) + row) * 8 + (c & 7);
          pAhi[idx] = hi; pAlo[idx] = lo;
        }
  }
  __syncthreads();

  // PV: u = S @ sol_t (cc chunk)
  f32x4 u[4][2];
  #pragma unroll
  for (int i = 0; i < 4; ++i)
    #pragma unroll
    for (int j = 0; j < 2; ++j) u[i][j] = (f32x4)(0.f);
  #pragma unroll
  for (int ks = 0; ks < 4; ++ks) {
    bf16x8 ah[4], al[4];
    #pragma unroll
    for (int m = 0; m < 4; ++m) {
      const int idx = (((ks * 4 + lk) * 128) + wr * 64 + m * 16 + lr) * 8;
      ah[m] = ldfrag(&pAhi[idx]);
      al[m] = ldfrag(&pAlo[idx]);
    }
    #pragma unroll
    for (int n = 0; n < 2; ++n) {
      const size_t c = cc * 128 + wc * 32 + n * 16 + lr;
      bf16x8 bh_ = ldfrag(srr + ((size_t)(ks * 4 + lk) * 512 + c) * 8);
      bf16x8 bl_ = ldfrag(srr + 65536 + ((size_t)(ks * 4 + lk) * 512 + c) * 8);
      #pragma unroll
      for (int m = 0; m < 4; ++m) {
        MFMA(u[m][n], ah[m], bh_);
        MFMA(u[m][n], ah[m], bl_);
        MFMA(u[m][n], al[m], bh_);
      }
    }
  }
  float nv[4][2][4];
  #pragma unroll
  for (int m = 0; m < 4; ++m)
    #pragma unroll
    for (int n = 0; n < 2; ++n) {
      const int col = wc * 32 + n * 16 + lr;
      #pragma unroll
      for (int q = 0; q < 4; ++q) {
        const int row = wr * 64 + m * 16 + lk * 4 + q;
        const float v = Vib[(size_t)row * LDV + cc * 128 + col] - u[m][n][q];
        nv[m][n][q] = v;
        if (!lead) Vib[(size_t)row * LDV + cc * 128 + col] = v;
      }
    }
  if (lead) {
    __syncthreads();   // all pA reads done; reuse pA buffers for rhs staging
    #pragma unroll
    for (int m = 0; m < 4; ++m)
      #pragma unroll
      for (int n = 0; n < 2; ++n) {
        const int col = wc * 32 + n * 16 + lr;
        #pragma unroll
        for (int q = 0; q < 4; ++q) {
          const int row = wr * 64 + m * 16 + lk * 4 + q;
          ushort hi, lo;
          split2(nv[m][n][q], hi, lo);
          const int idx = (((row >> 3) * 128) + col) * 8 + (row & 7);
          pAhi[idx] = hi; pAlo[idx] = lo;
        }
      }
    __syncthreads();
    f32x4 s2[4][2];
    #pragma unroll
    for (int i = 0; i < 4; ++i)
      #pragma unroll
      for (int j = 0; j < 2; ++j) s2[i][j] = (f32x4)(0.f);
    const size_t wb = (size_t)(bh * 16 + ib) * 16384;
    #pragma unroll
    for (int ks = 0; ks < 4; ++ks) {
      bf16x8 ah[4], al[4];
      #pragma unroll
      for (int m = 0; m < 4; ++m) {
        const size_t off = wb + ((size_t)(ks * 4 + lk) * 128 + wr * 64 + m * 16 + lr) * 8;
        ah[m] = ldfrag(Whi + off);
        al[m] = ldfrag(Wlo + off);
      }
      #pragma unroll
      for (int n = 0; n < 2; ++n) {
        const int idx = (((ks * 4 + lk) * 128) + wc * 32 + n * 16 + lr) * 8;
        bf16x8 bh_ = ldfrag(&pAhi[idx]);
        bf16x8 bl_ = ldfrag(&pAlo[idx]);
        #pragma unroll
        for (int m = 0; m < 4; ++m) {
          MFMA(s2[m][n], ah[m], bh_);
          MFMA(s2[m][n], ah[m], bl_);
          MFMA(s2[m][n], al[m], bh_);
        }
      }
    }
    #pragma unroll
    for (int m = 0; m < 4; ++m)
      #pragma unroll
      for (int n = 0; n < 2; ++n) {
        const int col = wc * 32 + n * 16 + lr;
        #pragma unroll
        for (int q = 0; q < 4; ++q) {
          const int row = wr * 64 + m * 16 + lk * 4 + q;
          const float v = s2[m][n][q];
          Vib[(size_t)row * LDV + cc * 128 + col] = v;
          ushort hi, lo;
          split2(v, hi, lo);
          const size_t so = ((size_t)(row >> 3) * 512 + cc * 128 + col) * 8 + (row & 7);
          srw[so] = hi; srw[65536 + so] = lo;
        }
      }
  }
}

// ---------------------------------------------------------------------------
// o_kernel v4 (round-15 best): O = tril(exp(Q K^T/16)) @ sol.
// Grid = 1024 blocks x 256 thr (4 waves): bid = bh(8, fastest -> XCD spread)
// | rh(4 x 32-row quarters) | ch(2 x 256-col halves) | ib(16, heavy first).
// Per jb: 32x128 Gram (rows disjoint across rh -> Gram dup 2x via ch only),
// P double-buffered in LDS (2 x 16KB) -> ONE barrier per jb; PV 32x256.
// 4 blocks/CU co-resident; setprio around MFMA clusters.
// ---------------------------------------------------------------------------
__global__ __launch_bounds__(256, 4) void o_kernel(
    const ushort* __restrict__ Qhi, const ushort* __restrict__ Qlo,
    const ushort* __restrict__ Khi, const ushort* __restrict__ Klo,
    const ushort* __restrict__ Sp0, const ushort* __restrict__ Sp1,
    ushort* __restrict__ Opack)
{
  __shared__ __align__(16) ushort Phi_s[2][16 * 32 * 8];  // 2 x 8 KB
  __shared__ __align__(16) ushort Plo_s[2][16 * 32 * 8];  // 2 x 8 KB
  const int bid = blockIdx.x;
  const int bh  = bid & 7;
  const int rh  = (bid >> 3) & 3;     // 32-row quarter of the ib block
  const int ch  = (bid >> 5) & 1;     // 256-col half of the head's 512
  const int ib  = 15 - (bid >> 6);    // 15..0: heaviest blocks launch first
  const int b = bh >> 2, h = bh & 3;
  const int tid = threadIdx.x;
  const int lane = tid & 63;
  const int wv = tid >> 6;            // 0..3
  const int lr = lane & 15, lk = lane >> 4;
  const ushort* Spb = b ? Sp1 : Sp0;

  const size_t qb = (size_t)(bh * 16 + ib) * 32768;
  f32x4 acc[2][4];
  #pragma unroll
  for (int i = 0; i < 2; ++i)
    #pragma unroll
    for (int j = 0; j < 4; ++j) acc[i][j] = (f32x4)(0.f);

  int pb = 0;
  for (int jb = 0; jb <= ib; ++jb) {
    // Gram: s = Q_ib[rh quarter, 32 rows] . K_jb^T (split, 3-term) -> 32x128
    f32x4 s1[2][2];
    #pragma unroll
    for (int i = 0; i < 2; ++i)
      #pragma unroll
      for (int j = 0; j < 2; ++j) s1[i][j] = (f32x4)(0.f);
    const size_t kb = (size_t)(bh * 16 + jb) * 32768;
    __builtin_amdgcn_s_setprio(1);
    #pragma unroll
    for (int ks = 0; ks < 8; ++ks) {
      bf16x8 ah[2], al[2];
      #pragma unroll
      for (int m = 0; m < 2; ++m) {
        const size_t off = qb + ((size_t)(ks * 4 + lk) * 128 + rh * 32 + m * 16 + lr) * 8;
        ah[m] = ldfrag(Qhi + off);
        al[m] = ldfrag(Qlo + off);
      }
      #pragma unroll
      for (int n = 0; n < 2; ++n) {
        const size_t off = kb + ((size_t)(ks * 4 + lk) * 128 + wv * 32 + n * 16 + lr) * 8;
        bf16x8 bh_ = ldfrag(Khi + off);
        bf16x8 bl_ = ldfrag(Klo + off);
        #pragma unroll
        for (int m = 0; m < 2; ++m) {
          MFMA(s1[m][n], ah[m], bh_);
          MFMA(s1[m][n], ah[m], bl_);
          MFMA(s1[m][n], al[m], bh_);
        }
      }
    }
    __builtin_amdgcn_s_setprio(0);
    // P = exp(s/16), tril-masked on diagonal block; split into buffer pb
    // (previous buffer pb^1 may still have readers -> no barrier needed here)
    #pragma unroll
    for (int m = 0; m < 2; ++m)
      #pragma unroll
      for (int n = 0; n < 2; ++n)
        #pragma unroll
        for (int q = 0; q < 4; ++q) {
          const int rloc = m * 16 + lk * 4 + q;        // 0..31
          const int c    = wv * 32 + n * 16 + lr;      // 0..127
          float e = __expf(s1[m][n][q] * 0.0625f);
          if (jb == ib && c > rh * 32 + rloc) e = 0.f;
          ushort hi, lo;
          split2(e, hi, lo);
          const int idx = (((c >> 3) * 32) + rloc) * 8 + (c & 7);
          Phi_s[pb][idx] = hi; Plo_s[pb][idx] = lo;
        }
    __syncthreads();   // single barrier per jb: P[pb] visible to all waves
    // acc += P @ sol (split, 3-term); sol fragments from global Spack
    const ushort* sjb = Spb + ((size_t)(h * 16 + jb) * 2) * 65536;
    __builtin_amdgcn_s_setprio(1);
    #pragma unroll
    for (int ks = 0; ks < 4; ++ks) {
      bf16x8 ah[2], al[2];
      #pragma unroll
      for (int m = 0; m < 2; ++m) {
        const int idx = (((ks * 4 + lk) * 32) + m * 16 + lr) * 8;
        ah[m] = ldfrag(&Phi_s[pb][idx]);
        al[m] = ldfrag(&Plo_s[pb][idx]);
      }
      #pragma unroll
      for (int n = 0; n < 4; ++n) {
        const size_t c = ch * 256 + wv * 64 + n * 16 + lr;
        bf16x8 bh_ = ldfrag(sjb + ((size_t)(ks * 4 + lk) * 512 + c) * 8);
        bf16x8 bl_ = ldfrag(sjb + 65536 + ((size_t)(ks * 4 + lk) * 512 + c) * 8);
        #pragma unroll
        for (int m = 0; m < 2; ++m) {
          MFMA(acc[m][n], ah[m], bh_);
          MFMA(acc[m][n], ah[m], bl_);
          MFMA(acc[m][n], al[m], bh_);
        }
      }
    }
    __builtin_amdgcn_s_setprio(0);
    pb ^= 1;
  }
  // write Opack (bf16 A-pack over the 2048 O-cols, K8 = 256)
  const int row_blk = b * 16 + ib;
  #pragma unroll
  for (int m = 0; m < 2; ++m)
    #pragma unroll
    for (int n = 0; n < 4; ++n) {
      const int col = h * 512 + ch * 256 + wv * 64 + n * 16 + lr;
      #pragma unroll
      for (int q = 0; q < 4; ++q) {
        const int row = rh * 32 + m * 16 + lk * 4 + q;
        Opack[((size_t)row_blk * 256 + (col >> 3)) * 1024 + row * 8 + (col & 7)] =
            f2bf(acc[m][n][q]);
      }
    }
}

// ---------------------------------------------------------------------------
extern "C" void kernel_launch(void* const* d_in, const int* in_sizes, int n_in,
                              void* d_out, int out_size, void* d_ws, size_t ws_size,
                              hipStream_t stream)
{
  const float* x  = (const float*)d_in[0];
  const float* Wq = (const float*)d_in[1];
  const float* Wk = (const float*)d_in[2];
  const float* Wv = (const float*)d_in[3];
  const float* Wo = (const float*)d_in[4];
  float* out = (float*)d_out;

  // Workspace (84 MB), phase-aliased:
  //  [0,16):  xpack(8) + Wqp/Wkp/Wvp(8)  ->  Qhi(8) + Qlo(8)
  //  [16,20): Wop (alive till end)
  //  [20,36): Q fp32  ->  Khi(8) + Klo(8)   (K pack AFTER Q pack consumed Q)
  //  [36,52): K fp32  ->  Whi(4)@36 + Wlo(4)@40 + Sroll(4)@44  ->  Spack1(16)@36
  //  [52,84): V fp32  ->  Opack(16)@52 + Spack0(16)@68
  char* base = (char*)d_ws;
  ushort* xpack = (ushort*)(base);
  ushort* Wqp   = (ushort*)(base + (8u  << 20));
  ushort* Wkp   = (ushort*)(base + (10u << 20));
  ushort* Wvp   = (ushort*)(base + (12u << 20));
  ushort* Wop   = (ushort*)(base + (16u << 20));
  float*  Q     = (float*) (base + (20u << 20));
  float*  K     = (float*) (base + (36u << 20));
  float*  V     = (float*) (base + (52u << 20));
  ushort* Qhi   = (ushort*)(base);
  ushort* Qlo   = (ushort*)(base + (8u  << 20));
  ushort* Khi   = (ushort*)(base + (20u << 20));
  ushort* Klo   = (ushort*)(base + (28u << 20));
  ushort* Whi   = (ushort*)(base + (36u << 20));
  ushort* Wlo   = (ushort*)(base + (40u << 20));
  ushort* SR    = (ushort*)(base + (44u << 20));   // Sroll, 2 slots x 2MB
  ushort* Sp1   = (ushort*)(base + (36u << 20));   // sol B-pack, batch 1
  ushort* Sp0   = (ushort*)(base + (68u << 20));   // sol B-pack, batch 0
  ushort* Opack = (ushort*)(base + (52u << 20));

  // Pack inputs (Wq+Wk fused into one launch)
  pack_x_kernel<<<(NROW * 128) / 256, 256, 0, stream>>>(x, xpack);
  pack_w2_kernel<<<dim3((1024 * 1024 / 8) / 256, 2), 256, 0, stream>>>(Wq, Wk, Wqp, Wkp);
  pack_w_kernel<<<(1024 * 2048 / 8) / 256, 256, 0, stream>>>(Wv, Wvp, 1024, 2048);
  pack_w_kernel<<<(2048 * 1024 / 8) / 256, 256, 0, stream>>>(Wo, Wop, 2048, 1024);

  // Projections (bf16 MFMA, fp32 out)
  gemm_bf16<<<dim3(DM / 128, NROW / 128), 256, 0, stream>>>(xpack, Wqp, Q, NROW, DM, DM);
  gemm_bf16<<<dim3(DM / 128, NROW / 128), 256, 0, stream>>>(xpack, Wkp, K, NROW, DM, DM);
  gemm_bf16<<<dim3(LDV / 128, NROW / 128), 256, 0, stream>>>(xpack, Wvp, V, NROW, LDV, DM);

  // Fused RoPE + split-pack: Q first (dest doesn't alias), then K (dest
  // reuses the Q fp32 region, dead after the first launch).
  rope_pack1_kernel<<<(NROW * 4 * 32) / 256, 256, 0, stream>>>(Q, Qhi, Qlo);
  rope_pack1_kernel<<<(NROW * 4 * 32) / 256, 256, 0, stream>>>(K, Khi, Klo);

  // Diagonal-block inverses, then the 16-step split-MFMA solve (in place on V)
  winv_kernel<<<dim3(NBLK, 8), 256, 0, stream>>>(Khi, Klo, Whi, Wlo);
  apply_w0_kernel<<<dim3(4, 8), 512, 0, stream>>>(Whi, Wlo, V, SR);
  for (int t = 0; t < NBLK - 1; ++t)
    solve_step_kernel<<<dim3(NBLK - 1 - t, 4, 8), 512, 0, stream>>>(Khi, Klo, Whi, Wlo, V, SR, t);

  // Pack sol to split B-packs (alias-safe ordering: b=1 first, then b=0)
  pack_sol_kernel<<<dim3(64, 2), 256, 0, stream>>>(V + (size_t)SEQ * LDV, Sp1);
  pack_sol_kernel<<<dim3(64, 2), 256, 0, stream>>>(V, Sp0);

  // O = tril(exp(QK^T/16)) @ sol  -> bf16 Opack
  o_kernel<<<1024, 256, 0, stream>>>(Qhi, Qlo, Khi, Klo, Sp0, Sp1, Opack);

  // out = O @ Wo (bf16 MFMA)
  gemm_bf16<<<dim3(DM / 128, NROW / 128), 256, 0, stream>>>(Opack, Wop, out, NROW, DM, LDV);
}